// Round 1
// baseline (2159.429 us; speedup 1.0000x reference)
//
#include <hip/hip_runtime.h>

#define N_ 4
#define H_ 128
#define W_ 128
#define C_ 256
#define P2_ 64
#define CELLS_ 16
#define HEADS_ 8
#define TOPK_ 4
#define SCALE_ 0.0625f
#define TOK_ (N_*H_*W_)   // 65536

// ---------------- pooling: xpool (4x4 cells) + window means ----------------
__global__ __launch_bounds__(256) void pool_kernel(
    const float* __restrict__ x1, const float* __restrict__ x2,
    float* __restrict__ xpool, float* __restrict__ xwm)
{
    int c = threadIdx.x;
    int blk = blockIdx.x;            // [0, 2*N*P2)
    int b   = blk >> 8;
    int rem = blk & 255;
    int n   = rem >> 6;
    int win = rem & 63;
    int wh = win >> 3, ww = win & 7;
    const float* x = (b ? x2 : x1);
    size_t nbase = (size_t)n * H_ * W_ * C_;
    size_t prow = (size_t)(b*N_ + n)*P2_ + win;
    float wsum = 0.f;
    #pragma unroll
    for (int cell = 0; cell < 16; ++cell) {
        int a = cell >> 2, d = cell & 3;
        int h0 = wh*16 + a*4, w0 = ww*16 + d*4;
        float s = 0.f;
        #pragma unroll
        for (int dy = 0; dy < 4; ++dy)
            #pragma unroll
            for (int dx = 0; dx < 4; ++dx)
                s += x[nbase + ((size_t)(h0+dy)*W_ + (w0+dx))*C_ + c];
        xpool[(prow*CELLS_ + cell)*C_ + c] = s * (1.f/16.f);
        wsum += s;
    }
    xwm[prow*C_ + c] = wsum * (1.f/256.f);
}

// ---------------- generic fp32 GEMM: out[M][*] = A[M][256] @ W[NO][256]^T + b ----
// tile: 64 tokens x 256 outputs per block; thread tile 4x16. Safe for in-place
// (A == out): each block reads only its own 64 rows, writes after all reads.
#define KC_ 32
__global__ __launch_bounds__(256) void gemm_k256(
    const float* A, const float* __restrict__ Wm,
    const float* __restrict__ bias, float* out, int out_stride)
{
    __shared__ float AsT[KC_][68];
    __shared__ float WsT[KC_][260];
    int tid = threadIdx.x;
    int row0   = blockIdx.x * 64;
    int cobase = blockIdx.y * 256;
    int tx = tid & 15, ty = tid >> 4;
    int t0 = ty * 4, c0 = tx * 16;
    float acc[4][16];
    #pragma unroll
    for (int i = 0; i < 4; ++i)
        #pragma unroll
        for (int j = 0; j < 16; ++j) acc[i][j] = 0.f;

    for (int ck = 0; ck < 256; ck += KC_) {
        #pragma unroll
        for (int j = 0; j < 2; ++j) {
            int q = j*256 + tid;
            int tok = q >> 3, c4 = (q & 7) * 4;
            float4 f = *(const float4*)(A + (size_t)(row0+tok)*256 + ck + c4);
            AsT[c4+0][tok] = f.x; AsT[c4+1][tok] = f.y;
            AsT[c4+2][tok] = f.z; AsT[c4+3][tok] = f.w;
        }
        #pragma unroll
        for (int j = 0; j < 8; ++j) {
            int q = j*256 + tid;
            int co = q >> 3, c4 = (q & 7) * 4;
            float4 f = *(const float4*)(Wm + (size_t)(cobase+co)*256 + ck + c4);
            WsT[c4+0][co] = f.x; WsT[c4+1][co] = f.y;
            WsT[c4+2][co] = f.z; WsT[c4+3][co] = f.w;
        }
        __syncthreads();
        #pragma unroll 4
        for (int c = 0; c < KC_; ++c) {
            float4 a4 = *(const float4*)&AsT[c][t0];
            float4 w0 = *(const float4*)&WsT[c][c0];
            float4 w1 = *(const float4*)&WsT[c][c0+4];
            float4 w2 = *(const float4*)&WsT[c][c0+8];
            float4 w3 = *(const float4*)&WsT[c][c0+12];
            float av[4] = {a4.x, a4.y, a4.z, a4.w};
            float wv[16] = {w0.x,w0.y,w0.z,w0.w, w1.x,w1.y,w1.z,w1.w,
                            w2.x,w2.y,w2.z,w2.w, w3.x,w3.y,w3.z,w3.w};
            #pragma unroll
            for (int i = 0; i < 4; ++i)
                #pragma unroll
                for (int j = 0; j < 16; ++j)
                    acc[i][j] += av[i] * wv[j];
        }
        __syncthreads();
    }
    float bv[16];
    #pragma unroll
    for (int j4 = 0; j4 < 4; ++j4) {
        float4 f = *(const float4*)(bias + cobase + c0 + j4*4);
        bv[j4*4+0]=f.x; bv[j4*4+1]=f.y; bv[j4*4+2]=f.z; bv[j4*4+3]=f.w;
    }
    #pragma unroll
    for (int i = 0; i < 4; ++i) {
        float* orow = out + (size_t)(row0+t0+i)*out_stride + cobase + c0;
        #pragma unroll
        for (int j4 = 0; j4 < 4; ++j4) {
            float4 f;
            f.x = acc[i][j4*4+0] + bv[j4*4+0];
            f.y = acc[i][j4*4+1] + bv[j4*4+1];
            f.z = acc[i][j4*4+2] + bv[j4*4+2];
            f.w = acc[i][j4*4+3] + bv[j4*4+3];
            *(float4*)(orow + j4*4) = f;
        }
    }
}

// ---------------- routing: logits + diag=1.0 + top-4 (tie -> lower index) ----
__global__ __launch_bounds__(64) void route_kernel(
    const float* __restrict__ qwin, const float* __restrict__ kwin,
    int* __restrict__ idx)
{
    int tid = threadIdx.x;            // 64 = one wave
    int blk = blockIdx.x;             // [0, 2*N*64)
    int pair = blk >> 8;
    int rem = blk & 255;
    int n = rem >> 6, i = rem & 63;
    int qb = (pair == 0) ? 1 : 0;     // idx1 = route(q2w, k1w)
    int kb = (pair == 0) ? 0 : 1;
    const float* q = qwin + ((size_t)(qb*N_+n)*64 + i)*256;
    const float* k = kwin + ((size_t)(kb*N_+n)*64 + tid)*256;
    float s = 0.f;
    for (int c = 0; c < 256; ++c) s += q[c]*k[c];
    s *= SCALE_;
    if (tid == i) s = 1.0f;
    int* orow = idx + ((size_t)pair*N_*64 + rem)*4;
    for (int t = 0; t < 4; ++t) {
        float v = s; int bi = tid;
        #pragma unroll
        for (int off = 32; off > 0; off >>= 1) {
            float ov = __shfl_down(v, off);
            int   oi = __shfl_down(bi, off);
            if (ov > v || (ov == v && oi < bi)) { v = ov; bi = oi; }
        }
        bi = __shfl(bi, 0);
        if (tid == 0) orow[t] = bi;
        if (tid == bi) s = -3.0e38f;
    }
}

// ---------------- LePE: depthwise 3x3 'SAME' conv over v image + bias --------
__global__ __launch_bounds__(256) void lepe_kernel(
    const float* __restrict__ v, const float* __restrict__ lw,
    const float* __restrict__ lb, float* __restrict__ out)
{
    int c = threadIdx.x;
    int blk = blockIdx.x;           // N*H*(W/32) = 2048
    int wseg = blk & 3;
    int h = (blk >> 2) & 127;
    int n = blk >> 9;
    float wk[9];
    #pragma unroll
    for (int t = 0; t < 9; ++t) wk[t] = lw[c*9 + t];
    float bias = lb[c];
    for (int px = 0; px < 32; ++px) {
        int w = wseg*32 + px;
        float acc = bias;
        #pragma unroll
        for (int ky = 0; ky < 3; ++ky) {
            int hh = h + ky - 1;
            if (hh < 0 || hh >= 128) continue;
            #pragma unroll
            for (int kx = 0; kx < 3; ++kx) {
                int wp = w + kx - 1;
                if (wp < 0 || wp >= 128) continue;
                acc += wk[ky*3+kx] * v[(((size_t)n*128 + hh)*128 + wp)*256 + c];
            }
        }
        out[(((size_t)n*128 + h)*128 + w)*256 + c] = acc;
    }
}

// ---------------- attention: per (n,window,head-pair); += into out ----------
__global__ __launch_bounds__(256) void attn_kernel(
    const float* __restrict__ qbuf, const float* __restrict__ kvp,
    const int* __restrict__ idx, float* out)
{
    int n   = blockIdx.x >> 6;
    int win = blockIdx.x & 63;
    int wh = win >> 3, ww = win & 7;
    int pix = threadIdx.x;
    int ph = pix >> 4, pw = pix & 15;
    int h = wh*16 + ph, w = ww*16 + pw;
    size_t prow = (((size_t)n*128 + h)*128 + w)*256;
    int sel[4];
    #pragma unroll
    for (int t = 0; t < 4; ++t) sel[t] = idx[((size_t)n*64 + win)*4 + t];
    const float* kvbase = kvp + (size_t)n*P2_*CELLS_*512;

    for (int e = 0; e < 2; ++e) {
        int hd = blockIdx.y*2 + e;
        int coff = hd*32;
        float q[32];
        #pragma unroll
        for (int d4 = 0; d4 < 8; ++d4) {
            float4 f = *(const float4*)(qbuf + prow + coff + d4*4);
            q[d4*4+0]=f.x; q[d4*4+1]=f.y; q[d4*4+2]=f.z; q[d4*4+3]=f.w;
        }
        float s[64];
        #pragma unroll
        for (int t = 0; t < 4; ++t) {
            const float* kr0 = kvbase + ((size_t)sel[t]*16)*512 + coff;
            #pragma unroll
            for (int k16 = 0; k16 < 16; ++k16) {
                const float* kr = kr0 + (size_t)k16*512;
                float acc = 0.f;
                #pragma unroll
                for (int d4 = 0; d4 < 8; ++d4) {
                    float4 f = *(const float4*)(kr + d4*4);
                    acc += q[d4*4+0]*f.x + q[d4*4+1]*f.y
                         + q[d4*4+2]*f.z + q[d4*4+3]*f.w;
                }
                s[t*16 + k16] = acc * SCALE_;
            }
        }
        float m = s[0];
        #pragma unroll
        for (int k = 1; k < 64; ++k) m = fmaxf(m, s[k]);
        float l = 0.f;
        #pragma unroll
        for (int k = 0; k < 64; ++k) { s[k] = __expf(s[k]-m); l += s[k]; }
        float inv = 1.f / l;
        float o[32];
        #pragma unroll
        for (int d = 0; d < 32; ++d) o[d] = 0.f;
        #pragma unroll
        for (int t = 0; t < 4; ++t) {
            const float* vr0 = kvbase + ((size_t)sel[t]*16)*512 + 256 + coff;
            #pragma unroll
            for (int k16 = 0; k16 < 16; ++k16) {
                float p = s[t*16 + k16];
                const float* vr = vr0 + (size_t)k16*512;
                #pragma unroll
                for (int d4 = 0; d4 < 8; ++d4) {
                    float4 f = *(const float4*)(vr + d4*4);
                    o[d4*4+0] += p*f.x; o[d4*4+1] += p*f.y;
                    o[d4*4+2] += p*f.z; o[d4*4+3] += p*f.w;
                }
            }
        }
        float* op = out + prow + coff;
        #pragma unroll
        for (int d4 = 0; d4 < 8; ++d4) {
            float4 cur = *(const float4*)(op + d4*4);
            cur.x += o[d4*4+0]*inv; cur.y += o[d4*4+1]*inv;
            cur.z += o[d4*4+2]*inv; cur.w += o[d4*4+3]*inv;
            *(float4*)(op + d4*4) = cur;
        }
    }
}

extern "C" void kernel_launch(void* const* d_in, const int* in_sizes, int n_in,
                              void* d_out, int out_size, void* d_ws, size_t ws_size,
                              hipStream_t stream)
{
    const float* x1   = (const float*)d_in[0];
    const float* x2   = (const float*)d_in[1];
    const float* Wqkv = (const float*)d_in[2];
    const float* bqkv = (const float*)d_in[3];
    const float* lw   = (const float*)d_in[4];
    const float* lb   = (const float*)d_in[5];
    const float* Wo   = (const float*)d_in[6];
    const float* bo   = (const float*)d_in[7];
    float* out1 = (float*)d_out;
    float* out2 = out1 + (size_t)TOK_*C_;

    float* ws    = (float*)d_ws;
    float* xpool = ws;                          // 2*N*P2*16*256  = 2,097,152 f
    float* xwm   = xpool + 2097152;             // 2*N*P2*256     =   131,072 f
    float* kvp   = xwm   + 131072;              // 2*N*P2*16*512  = 4,194,304 f
    float* qwin  = kvp   + 4194304;             //                  131,072 f
    float* kwin  = qwin  + 131072;              //                  131,072 f
    int*   idx   = (int*)(kwin + 131072);       // 2*N*64*4       =     2,048 i
    float* buf   = (float*)(idx + 2048);        // TOK*C          = 16,777,216 f

    // 1) pooled image + window means (both branches)
    pool_kernel<<<dim3(512), dim3(256), 0, stream>>>(x1, x2, xpool, xwm);
    // 2) kv_pool = xpool @ Wkv^T + bkv   (M=8192, NO=512)
    gemm_k256<<<dim3(128,2), dim3(256), 0, stream>>>(xpool, Wqkv + 256*256, bqkv + 256, kvp, 512);
    // 3) window-mean projections (M=512)
    gemm_k256<<<dim3(8,1), dim3(256), 0, stream>>>(xwm, Wqkv,           bqkv,       qwin, 256);
    gemm_k256<<<dim3(8,1), dim3(256), 0, stream>>>(xwm, Wqkv + 256*256, bqkv + 256, kwin, 256);
    // 4) routing (both pairs)
    route_kernel<<<dim3(512), dim3(64), 0, stream>>>(qwin, kwin, idx);
    // 5) v1 -> buf ; lepe1 = conv(v1) -> out1
    gemm_k256<<<dim3(1024,1), dim3(256), 0, stream>>>(x1, Wqkv + 512*256, bqkv + 512, buf, 256);
    lepe_kernel<<<dim3(2048), dim3(256), 0, stream>>>(buf, lw, lb, out1);
    // 6) v2 -> buf ; lepe2 -> out2
    gemm_k256<<<dim3(1024,1), dim3(256), 0, stream>>>(x2, Wqkv + 512*256, bqkv + 512, buf, 256);
    lepe_kernel<<<dim3(2048), dim3(256), 0, stream>>>(buf, lw, lb, out2);
    // 7) q2 -> buf ; attend(q2, kv1, idx1) += out1
    gemm_k256<<<dim3(1024,1), dim3(256), 0, stream>>>(x2, Wqkv, bqkv, buf, 256);
    attn_kernel<<<dim3(256,4), dim3(256), 0, stream>>>(buf, kvp, idx, out1);
    // 8) q1 -> buf ; attend(q1, kv2, idx2) += out2
    gemm_k256<<<dim3(1024,1), dim3(256), 0, stream>>>(x1, Wqkv, bqkv, buf, 256);
    attn_kernel<<<dim3(256,4), dim3(256), 0, stream>>>(buf, kvp + 2097152, idx + N_*64*4, out2);
    // 9) final projection, in-place on d_out
    gemm_k256<<<dim3(1024,1), dim3(256), 0, stream>>>(out1, Wo, bo, out1, 256);
    gemm_k256<<<dim3(1024,1), dim3(256), 0, stream>>>(out2, Wo, bo, out2, 256);
}

// Round 2
// 1703.745 us; speedup vs baseline: 1.2675x; 1.2675x over previous
//
#include <hip/hip_runtime.h>

#define N_ 4
#define H_ 128
#define W_ 128
#define C_ 256
#define P2_ 64
#define CELLS_ 16
#define HEADS_ 8
#define TOPK_ 4
#define SCALE_ 0.0625f
#define TOK_ (N_*H_*W_)   // 65536

// ---------------- pooling: xpool (4x4 cells) + window means ----------------
__global__ __launch_bounds__(256) void pool_kernel(
    const float* __restrict__ x1, const float* __restrict__ x2,
    float* __restrict__ xpool, float* __restrict__ xwm)
{
    int c = threadIdx.x;
    int blk = blockIdx.x;            // [0, 2*N*P2)
    int b   = blk >> 8;
    int rem = blk & 255;
    int n   = rem >> 6;
    int win = rem & 63;
    int wh = win >> 3, ww = win & 7;
    const float* x = (b ? x2 : x1);
    size_t nbase = (size_t)n * H_ * W_ * C_;
    size_t prow = (size_t)(b*N_ + n)*P2_ + win;
    float wsum = 0.f;
    #pragma unroll
    for (int cell = 0; cell < 16; ++cell) {
        int a = cell >> 2, d = cell & 3;
        int h0 = wh*16 + a*4, w0 = ww*16 + d*4;
        float s = 0.f;
        #pragma unroll
        for (int dy = 0; dy < 4; ++dy)
            #pragma unroll
            for (int dx = 0; dx < 4; ++dx)
                s += x[nbase + ((size_t)(h0+dy)*W_ + (w0+dx))*C_ + c];
        xpool[(prow*CELLS_ + cell)*C_ + c] = s * (1.f/16.f);
        wsum += s;
    }
    xwm[prow*C_ + c] = wsum * (1.f/256.f);
}

// ---------------- generic fp32 GEMM: out[M][*] = A[M][256] @ W[NO][256]^T + b ----
#define KC_ 32
__global__ __launch_bounds__(256) void gemm_k256(
    const float* A, const float* __restrict__ Wm,
    const float* __restrict__ bias, float* out, int out_stride)
{
    __shared__ float AsT[KC_][68];
    __shared__ float WsT[KC_][260];
    int tid = threadIdx.x;
    int row0   = blockIdx.x * 64;
    int cobase = blockIdx.y * 256;
    int tx = tid & 15, ty = tid >> 4;
    int t0 = ty * 4, c0 = tx * 16;
    float acc[4][16];
    #pragma unroll
    for (int i = 0; i < 4; ++i)
        #pragma unroll
        for (int j = 0; j < 16; ++j) acc[i][j] = 0.f;

    for (int ck = 0; ck < 256; ck += KC_) {
        #pragma unroll
        for (int j = 0; j < 2; ++j) {
            int q = j*256 + tid;
            int tok = q >> 3, c4 = (q & 7) * 4;
            float4 f = *(const float4*)(A + (size_t)(row0+tok)*256 + ck + c4);
            AsT[c4+0][tok] = f.x; AsT[c4+1][tok] = f.y;
            AsT[c4+2][tok] = f.z; AsT[c4+3][tok] = f.w;
        }
        #pragma unroll
        for (int j = 0; j < 8; ++j) {
            int q = j*256 + tid;
            int co = q >> 3, c4 = (q & 7) * 4;
            float4 f = *(const float4*)(Wm + (size_t)(cobase+co)*256 + ck + c4);
            WsT[c4+0][co] = f.x; WsT[c4+1][co] = f.y;
            WsT[c4+2][co] = f.z; WsT[c4+3][co] = f.w;
        }
        __syncthreads();
        #pragma unroll 4
        for (int c = 0; c < KC_; ++c) {
            float4 a4 = *(const float4*)&AsT[c][t0];
            float4 w0 = *(const float4*)&WsT[c][c0];
            float4 w1 = *(const float4*)&WsT[c][c0+4];
            float4 w2 = *(const float4*)&WsT[c][c0+8];
            float4 w3 = *(const float4*)&WsT[c][c0+12];
            float av[4] = {a4.x, a4.y, a4.z, a4.w};
            float wv[16] = {w0.x,w0.y,w0.z,w0.w, w1.x,w1.y,w1.z,w1.w,
                            w2.x,w2.y,w2.z,w2.w, w3.x,w3.y,w3.z,w3.w};
            #pragma unroll
            for (int i = 0; i < 4; ++i)
                #pragma unroll
                for (int j = 0; j < 16; ++j)
                    acc[i][j] += av[i] * wv[j];
        }
        __syncthreads();
    }
    float bv[16];
    #pragma unroll
    for (int j4 = 0; j4 < 4; ++j4) {
        float4 f = *(const float4*)(bias + cobase + c0 + j4*4);
        bv[j4*4+0]=f.x; bv[j4*4+1]=f.y; bv[j4*4+2]=f.z; bv[j4*4+3]=f.w;
    }
    #pragma unroll
    for (int i = 0; i < 4; ++i) {
        float* orow = out + (size_t)(row0+t0+i)*out_stride + cobase + c0;
        #pragma unroll
        for (int j4 = 0; j4 < 4; ++j4) {
            float4 f;
            f.x = acc[i][j4*4+0] + bv[j4*4+0];
            f.y = acc[i][j4*4+1] + bv[j4*4+1];
            f.z = acc[i][j4*4+2] + bv[j4*4+2];
            f.w = acc[i][j4*4+3] + bv[j4*4+3];
            *(float4*)(orow + j4*4) = f;
        }
    }
}

// ---------------- routing: logits + diag=1.0 + top-4 (tie -> lower index) ----
__global__ __launch_bounds__(64) void route_kernel(
    const float* __restrict__ qwin, const float* __restrict__ kwin,
    int* __restrict__ idx)
{
    int tid = threadIdx.x;            // 64 = one wave
    int blk = blockIdx.x;             // [0, 2*N*64)
    int pair = blk >> 8;
    int rem = blk & 255;
    int n = rem >> 6, i = rem & 63;
    int qb = (pair == 0) ? 1 : 0;     // idx1 = route(q2w, k1w)
    int kb = (pair == 0) ? 0 : 1;
    const float* q = qwin + ((size_t)(qb*N_+n)*64 + i)*256;
    const float* k = kwin + ((size_t)(kb*N_+n)*64 + tid)*256;
    float s = 0.f;
    for (int c = 0; c < 256; ++c) s += q[c]*k[c];
    s *= SCALE_;
    if (tid == i) s = 1.0f;
    int* orow = idx + ((size_t)pair*N_*64 + rem)*4;
    for (int t = 0; t < 4; ++t) {
        float v = s; int bi = tid;
        #pragma unroll
        for (int off = 32; off > 0; off >>= 1) {
            float ov = __shfl_down(v, off);
            int   oi = __shfl_down(bi, off);
            if (ov > v || (ov == v && oi < bi)) { v = ov; bi = oi; }
        }
        bi = __shfl(bi, 0);
        if (tid == 0) orow[t] = bi;
        if (tid == bi) s = -3.0e38f;
    }
}

// ---------------- LePE: depthwise 3x3 'SAME' conv over v image + bias --------
__global__ __launch_bounds__(256) void lepe_kernel(
    const float* __restrict__ v, const float* __restrict__ lw,
    const float* __restrict__ lb, float* __restrict__ out)
{
    int c = threadIdx.x;
    int blk = blockIdx.x;           // N*H*(W/32) = 2048
    int wseg = blk & 3;
    int h = (blk >> 2) & 127;
    int n = blk >> 9;
    float wk[9];
    #pragma unroll
    for (int t = 0; t < 9; ++t) wk[t] = lw[c*9 + t];
    float bias = lb[c];
    for (int px = 0; px < 32; ++px) {
        int w = wseg*32 + px;
        float acc = bias;
        #pragma unroll
        for (int ky = 0; ky < 3; ++ky) {
            int hh = h + ky - 1;
            if (hh < 0 || hh >= 128) continue;
            #pragma unroll
            for (int kx = 0; kx < 3; ++kx) {
                int wp = w + kx - 1;
                if (wp < 0 || wp >= 128) continue;
                acc += wk[ky*3+kx] * v[(((size_t)n*128 + hh)*128 + wp)*256 + c];
            }
        }
        out[(((size_t)n*128 + h)*128 + w)*256 + c] = acc;
    }
}

// ---------------- attention v2: LDS-staged KV + online softmax ----------------
// block = (n*64+win, head-pair). 256 threads = 256 pixels. 2 heads per block.
__global__ __launch_bounds__(256) void attn_kernel(
    const float* __restrict__ qbuf, const float* __restrict__ kvp,
    const int* __restrict__ idx, float* __restrict__ out)
{
    __shared__ float kb[2][64][32];   // [head][key][dim]  16 KB
    __shared__ float vb[2][64][32];   // 16 KB
    __shared__ int sel[4];
    int n   = blockIdx.x >> 6;
    int win = blockIdx.x & 63;
    int hd0 = blockIdx.y * 2;
    int tid = threadIdx.x;
    if (tid < 4) sel[tid] = idx[((size_t)n*64 + win)*4 + tid];
    __syncthreads();
    const float* kvbase = kvp + (size_t)n*(64*16*512);
    // stage K,V for both heads: 2 heads * 64 keys * 8 float4 = 1024 float4 each
    #pragma unroll
    for (int i = 0; i < 4; ++i) {
        int f = i*256 + tid;
        int e   = f >> 9;         // head within pair
        int key = (f >> 3) & 63;  // 4 windows * 16 cells
        int d4  = f & 7;
        const float* src = kvbase + ((size_t)(sel[key>>4]*16 + (key&15)))*512
                         + (hd0+e)*32 + d4*4;
        *(float4*)&kb[e][key][d4*4] = *(const float4*)src;
        *(float4*)&vb[e][key][d4*4] = *(const float4*)(src + 256);
    }
    __syncthreads();

    int ph = tid >> 4, pw = tid & 15;
    int h = (win >> 3)*16 + ph, w = (win & 7)*16 + pw;
    size_t prow = (((size_t)n*128 + h)*128 + w)*256;

    #pragma unroll
    for (int e = 0; e < 2; ++e) {
        int coff = (hd0 + e)*32;
        float q[32];
        #pragma unroll
        for (int d4 = 0; d4 < 8; ++d4) {
            float4 f = *(const float4*)(qbuf + prow + coff + d4*4);
            q[d4*4+0]=f.x; q[d4*4+1]=f.y; q[d4*4+2]=f.z; q[d4*4+3]=f.w;
        }
        float o[32];
        #pragma unroll
        for (int d = 0; d < 32; ++d) o[d] = 0.f;
        float m = -3.0e38f, l = 0.f;
        #pragma unroll
        for (int c4 = 0; c4 < 4; ++c4) {
            float sc[16];
            float cmax = -3.0e38f;
            #pragma unroll
            for (int k = 0; k < 16; ++k) {
                const float* kr = &kb[e][c4*16 + k][0];
                float acc = 0.f;
                #pragma unroll
                for (int d4 = 0; d4 < 8; ++d4) {
                    float4 f = *(const float4*)(kr + d4*4);
                    acc += q[d4*4+0]*f.x + q[d4*4+1]*f.y
                         + q[d4*4+2]*f.z + q[d4*4+3]*f.w;
                }
                sc[k] = acc * SCALE_;
                cmax = fmaxf(cmax, sc[k]);
            }
            float newm = fmaxf(m, cmax);
            float alpha = __expf(m - newm);   // first iter: exp(-inf)=0
            l *= alpha;
            #pragma unroll
            for (int d = 0; d < 32; ++d) o[d] *= alpha;
            #pragma unroll
            for (int k = 0; k < 16; ++k) {
                float p = __expf(sc[k] - newm);
                l += p;
                const float* vr = &vb[e][c4*16 + k][0];
                #pragma unroll
                for (int d4 = 0; d4 < 8; ++d4) {
                    float4 f = *(const float4*)(vr + d4*4);
                    o[d4*4+0] += p*f.x; o[d4*4+1] += p*f.y;
                    o[d4*4+2] += p*f.z; o[d4*4+3] += p*f.w;
                }
            }
            m = newm;
        }
        float inv = 1.f / l;
        float* op = out + prow + coff;
        #pragma unroll
        for (int d4 = 0; d4 < 8; ++d4) {
            float4 cur = *(const float4*)(op + d4*4);
            cur.x += o[d4*4+0]*inv; cur.y += o[d4*4+1]*inv;
            cur.z += o[d4*4+2]*inv; cur.w += o[d4*4+3]*inv;
            *(float4*)(op + d4*4) = cur;
        }
    }
}

extern "C" void kernel_launch(void* const* d_in, const int* in_sizes, int n_in,
                              void* d_out, int out_size, void* d_ws, size_t ws_size,
                              hipStream_t stream)
{
    const float* x1   = (const float*)d_in[0];
    const float* x2   = (const float*)d_in[1];
    const float* Wqkv = (const float*)d_in[2];
    const float* bqkv = (const float*)d_in[3];
    const float* lw   = (const float*)d_in[4];
    const float* lb   = (const float*)d_in[5];
    const float* Wo   = (const float*)d_in[6];
    const float* bo   = (const float*)d_in[7];
    float* out1 = (float*)d_out;
    float* out2 = out1 + (size_t)TOK_*C_;

    float* ws    = (float*)d_ws;
    float* xpool = ws;                          // 2*N*P2*16*256  = 2,097,152 f
    float* xwm   = xpool + 2097152;             // 2*N*P2*256     =   131,072 f
    float* kvp   = xwm   + 131072;              // 2*N*P2*16*512  = 4,194,304 f
    float* qwin  = kvp   + 4194304;             //                  131,072 f
    float* kwin  = qwin  + 131072;              //                  131,072 f
    int*   idx   = (int*)(kwin + 131072);       // 2*N*64*4       =     2,048 i
    float* buf   = (float*)(idx + 2048);        // TOK*C          = 16,777,216 f

    // 1) pooled image + window means (both branches)
    pool_kernel<<<dim3(512), dim3(256), 0, stream>>>(x1, x2, xpool, xwm);
    // 2) kv_pool = xpool @ Wkv^T + bkv   (M=8192, NO=512)
    gemm_k256<<<dim3(128,2), dim3(256), 0, stream>>>(xpool, Wqkv + 256*256, bqkv + 256, kvp, 512);
    // 3) window-mean projections (M=512)
    gemm_k256<<<dim3(8,1), dim3(256), 0, stream>>>(xwm, Wqkv,           bqkv,       qwin, 256);
    gemm_k256<<<dim3(8,1), dim3(256), 0, stream>>>(xwm, Wqkv + 256*256, bqkv + 256, kwin, 256);
    // 4) routing (both pairs)
    route_kernel<<<dim3(512), dim3(64), 0, stream>>>(qwin, kwin, idx);
    // 5) v1 -> buf ; lepe1 = conv(v1) -> out1
    gemm_k256<<<dim3(1024,1), dim3(256), 0, stream>>>(x1, Wqkv + 512*256, bqkv + 512, buf, 256);
    lepe_kernel<<<dim3(2048), dim3(256), 0, stream>>>(buf, lw, lb, out1);
    // 6) v2 -> buf ; lepe2 -> out2
    gemm_k256<<<dim3(1024,1), dim3(256), 0, stream>>>(x2, Wqkv + 512*256, bqkv + 512, buf, 256);
    lepe_kernel<<<dim3(2048), dim3(256), 0, stream>>>(buf, lw, lb, out2);
    // 7) q2 -> buf ; attend(q2, kv1, idx1) += out1
    gemm_k256<<<dim3(1024,1), dim3(256), 0, stream>>>(x2, Wqkv, bqkv, buf, 256);
    attn_kernel<<<dim3(256,4), dim3(256), 0, stream>>>(buf, kvp, idx, out1);
    // 8) q1 -> buf ; attend(q1, kv2, idx2) += out2
    gemm_k256<<<dim3(1024,1), dim3(256), 0, stream>>>(x1, Wqkv, bqkv, buf, 256);
    attn_kernel<<<dim3(256,4), dim3(256), 0, stream>>>(buf, kvp + 2097152, idx + N_*64*4, out2);
    // 9) final projection, in-place on d_out
    gemm_k256<<<dim3(1024,1), dim3(256), 0, stream>>>(out1, Wo, bo, out1, 256);
    gemm_k256<<<dim3(1024,1), dim3(256), 0, stream>>>(out2, Wo, bo, out2, 256);
}

// Round 3
// 867.919 us; speedup vs baseline: 2.4881x; 1.9630x over previous
//
#include <hip/hip_runtime.h>

#define N_ 4
#define H_ 128
#define W_ 128
#define C_ 256
#define P2_ 64
#define CELLS_ 16
#define HEADS_ 8
#define TOPK_ 4
#define SCALE_ 0.0625f
#define TOK_ (N_*H_*W_)   // 65536

typedef short short8 __attribute__((ext_vector_type(8)));
typedef float f32x4  __attribute__((ext_vector_type(4)));

// ---------------- pooling: xpool (4x4 cells) + window means ----------------
__global__ __launch_bounds__(256) void pool_kernel(
    const float* __restrict__ x1, const float* __restrict__ x2,
    float* __restrict__ xpool, float* __restrict__ xwm)
{
    int c = threadIdx.x;
    int blk = blockIdx.x;            // [0, 2*N*P2)
    int b   = blk >> 8;
    int rem = blk & 255;
    int n   = rem >> 6;
    int win = rem & 63;
    int wh = win >> 3, ww = win & 7;
    const float* x = (b ? x2 : x1);
    size_t nbase = (size_t)n * H_ * W_ * C_;
    size_t prow = (size_t)(b*N_ + n)*P2_ + win;
    float wsum = 0.f;
    #pragma unroll
    for (int cell = 0; cell < 16; ++cell) {
        int a = cell >> 2, d = cell & 3;
        int h0 = wh*16 + a*4, w0 = ww*16 + d*4;
        float s = 0.f;
        #pragma unroll
        for (int dy = 0; dy < 4; ++dy)
            #pragma unroll
            for (int dx = 0; dx < 4; ++dx)
                s += x[nbase + ((size_t)(h0+dy)*W_ + (w0+dx))*C_ + c];
        xpool[(prow*CELLS_ + cell)*C_ + c] = s * (1.f/16.f);
        wsum += s;
    }
    xwm[prow*C_ + c] = wsum * (1.f/256.f);
}

// ---------------- W pre-split: fp32 -> bf16 hi (truncate) + lo (RNE) --------
// combined table rows: [0,768) = Wqkv, [768,1024) = Wo.  262144 elems.
__global__ __launch_bounds__(256) void wsplit_kernel(
    const float* __restrict__ Wqkv, const float* __restrict__ Wo,
    ushort* __restrict__ Wh, ushort* __restrict__ Wl)
{
    int e = (blockIdx.x*256 + threadIdx.x) * 4;
    const float* src = (e < 768*256) ? (Wqkv + e) : (Wo + (e - 768*256));
    float4 f = *(const float4*)src;
    float fv[4] = {f.x, f.y, f.z, f.w};
    ushort hu[4], lu[4];
    #pragma unroll
    for (int j = 0; j < 4; ++j) {
        unsigned u = __float_as_uint(fv[j]);
        hu[j] = (ushort)(u >> 16);                       // truncated bf16 (exact)
        float hif = __uint_as_float(u & 0xFFFF0000u);
        unsigned ul = __float_as_uint(fv[j] - hif);      // exact residual
        ul = ul + 0x7FFFu + ((ul >> 16) & 1u);           // RNE to bf16
        lu[j] = (ushort)(ul >> 16);
    }
    *(uint2*)&Wh[e] = *(uint2*)hu;
    *(uint2*)&Wl[e] = *(uint2*)lu;
}

// ---------------- MFMA GEMM: out[M][*] = A[M][256] @ W[rows][256]^T + b -----
// bf16x3 split-precision. Block: 64 rows x 256 cols, 4 waves (wave tile 64x64).
// A fp32 split on the fly; W pre-split (Wh/Wl). In-place safe for out==A when
// gridDim.y==1 (block owns its 64 rows exclusively; writes only in epilogue).
#define AST 40   // LDS row stride (ushorts) = 80 B = 20 banks -> <=2-way alias
__global__ __launch_bounds__(256) void gemm_mfma(
    const float* __restrict__ A,
    const ushort* __restrict__ Wh, const ushort* __restrict__ Wl,
    int w_base, const float* __restrict__ bias,
    float* __restrict__ out, int out_stride)
{
    __shared__ ushort Ah[64*AST],  Al[64*AST];    // 5120 B each
    __shared__ ushort Bh[256*AST], Bl[256*AST];   // 20480 B each
    int tid = threadIdx.x;
    int row0 = blockIdx.x * 64;
    int cob  = blockIdx.y * 256;
    int wv = tid >> 6, lane = tid & 63;
    int quad = lane >> 4, l15 = lane & 15;

    f32x4 acc[4][4];
    #pragma unroll
    for (int mt = 0; mt < 4; ++mt)
        #pragma unroll
        for (int nt = 0; nt < 4; ++nt)
            acc[mt][nt] = f32x4{0.f, 0.f, 0.f, 0.f};

    int srow = tid >> 2;            // 0..63
    int skk  = (tid & 3) * 8;       // 0,8,16,24
    const float*  aptr = A  + (size_t)(row0 + srow)*256 + skk;
    const ushort* whp  = Wh + (size_t)(w_base + cob + srow)*256 + skk;
    const ushort* wlp  = Wl + (size_t)(w_base + cob + srow)*256 + skk;

    for (int ck = 0; ck < 256; ck += 32) {
        // ---- stage A chunk (64x32 fp32 -> split bf16) ----
        float4 f0 = *(const float4*)(aptr + ck);
        float4 f1 = *(const float4*)(aptr + ck + 4);
        float fv[8] = {f0.x,f0.y,f0.z,f0.w, f1.x,f1.y,f1.z,f1.w};
        ushort hu[8], lu[8];
        #pragma unroll
        for (int j = 0; j < 8; ++j) {
            unsigned u = __float_as_uint(fv[j]);
            hu[j] = (ushort)(u >> 16);
            float hif = __uint_as_float(u & 0xFFFF0000u);
            unsigned ul = __float_as_uint(fv[j] - hif);
            ul = ul + 0x7FFFu + ((ul >> 16) & 1u);
            lu[j] = (ushort)(ul >> 16);
        }
        *(uint4*)&Ah[srow*AST + skk] = *(uint4*)hu;
        *(uint4*)&Al[srow*AST + skk] = *(uint4*)lu;
        // ---- stage W chunk (256x32 bf16 copy) ----
        #pragma unroll
        for (int p = 0; p < 4; ++p) {
            int r = p*64 + srow;
            *(uint4*)&Bh[r*AST + skk] = *(const uint4*)(whp + (size_t)p*64*256 + ck);
            *(uint4*)&Bl[r*AST + skk] = *(const uint4*)(wlp + (size_t)p*64*256 + ck);
        }
        __syncthreads();
        // ---- compute: wave tile 64x64 = 4x4 of 16x16, 3 MFMAs each ----
        short8 bh[4], bl[4];
        #pragma unroll
        for (int nt = 0; nt < 4; ++nt) {
            int r = wv*64 + nt*16 + l15;
            bh[nt] = *(const short8*)&Bh[r*AST + quad*8];
            bl[nt] = *(const short8*)&Bl[r*AST + quad*8];
        }
        #pragma unroll
        for (int mt = 0; mt < 4; ++mt) {
            int r = mt*16 + l15;
            short8 ah = *(const short8*)&Ah[r*AST + quad*8];
            short8 al = *(const short8*)&Al[r*AST + quad*8];
            #pragma unroll
            for (int nt = 0; nt < 4; ++nt) {
                acc[mt][nt] = __builtin_amdgcn_mfma_f32_16x16x32_bf16(ah, bh[nt], acc[mt][nt], 0, 0, 0);
                acc[mt][nt] = __builtin_amdgcn_mfma_f32_16x16x32_bf16(ah, bl[nt], acc[mt][nt], 0, 0, 0);
                acc[mt][nt] = __builtin_amdgcn_mfma_f32_16x16x32_bf16(al, bh[nt], acc[mt][nt], 0, 0, 0);
            }
        }
        __syncthreads();
    }
    // ---- epilogue: C/D layout col=lane&15, row=quad*4+reg ----
    float bv[4];
    #pragma unroll
    for (int nt = 0; nt < 4; ++nt) bv[nt] = bias[cob + wv*64 + nt*16 + l15];
    #pragma unroll
    for (int mt = 0; mt < 4; ++mt) {
        int rg = row0 + mt*16 + quad*4;
        #pragma unroll
        for (int r = 0; r < 4; ++r) {
            float* orow = out + (size_t)(rg + r)*out_stride + cob + wv*64 + l15;
            #pragma unroll
            for (int nt = 0; nt < 4; ++nt)
                orow[nt*16] = acc[mt][nt][r] + bv[nt];
        }
    }
}

// ---------------- routing: logits + diag=1.0 + top-4 (tie -> lower index) ----
__global__ __launch_bounds__(64) void route_kernel(
    const float* __restrict__ qwin, const float* __restrict__ kwin,
    int* __restrict__ idx)
{
    int tid = threadIdx.x;            // 64 = one wave
    int blk = blockIdx.x;             // [0, 2*N*64)
    int pair = blk >> 8;
    int rem = blk & 255;
    int n = rem >> 6, i = rem & 63;
    int qb = (pair == 0) ? 1 : 0;     // idx1 = route(q2w, k1w)
    int kb = (pair == 0) ? 0 : 1;
    const float* q = qwin + ((size_t)(qb*N_+n)*64 + i)*256;
    const float* k = kwin + ((size_t)(kb*N_+n)*64 + tid)*256;
    float s = 0.f;
    for (int c = 0; c < 256; ++c) s += q[c]*k[c];
    s *= SCALE_;
    if (tid == i) s = 1.0f;
    int* orow = idx + ((size_t)pair*N_*64 + rem)*4;
    for (int t = 0; t < 4; ++t) {
        float v = s; int bi = tid;
        #pragma unroll
        for (int off = 32; off > 0; off >>= 1) {
            float ov = __shfl_down(v, off);
            int   oi = __shfl_down(bi, off);
            if (ov > v || (ov == v && oi < bi)) { v = ov; bi = oi; }
        }
        bi = __shfl(bi, 0);
        if (tid == 0) orow[t] = bi;
        if (tid == bi) s = -3.0e38f;
    }
}

// ---------------- LePE: depthwise 3x3 'SAME' conv over v image + bias --------
__global__ __launch_bounds__(256) void lepe_kernel(
    const float* __restrict__ v, const float* __restrict__ lw,
    const float* __restrict__ lb, float* __restrict__ out)
{
    int c = threadIdx.x;
    int blk = blockIdx.x;           // N*H*(W/32) = 2048
    int wseg = blk & 3;
    int h = (blk >> 2) & 127;
    int n = blk >> 9;
    float wk[9];
    #pragma unroll
    for (int t = 0; t < 9; ++t) wk[t] = lw[c*9 + t];
    float bias = lb[c];
    for (int px = 0; px < 32; ++px) {
        int w = wseg*32 + px;
        float acc = bias;
        #pragma unroll
        for (int ky = 0; ky < 3; ++ky) {
            int hh = h + ky - 1;
            if (hh < 0 || hh >= 128) continue;
            #pragma unroll
            for (int kx = 0; kx < 3; ++kx) {
                int wp = w + kx - 1;
                if (wp < 0 || wp >= 128) continue;
                acc += wk[ky*3+kx] * v[(((size_t)n*128 + hh)*128 + wp)*256 + c];
            }
        }
        out[(((size_t)n*128 + h)*128 + w)*256 + c] = acc;
    }
}

// ---------------- attention: LDS-staged KV + online softmax ------------------
__global__ __launch_bounds__(256) void attn_kernel(
    const float* __restrict__ qbuf, const float* __restrict__ kvp,
    const int* __restrict__ idx, float* __restrict__ out)
{
    __shared__ float kb[2][64][32];   // [head][key][dim]  16 KB
    __shared__ float vb[2][64][32];   // 16 KB
    __shared__ int sel[4];
    int n   = blockIdx.x >> 6;
    int win = blockIdx.x & 63;
    int hd0 = blockIdx.y * 2;
    int tid = threadIdx.x;
    if (tid < 4) sel[tid] = idx[((size_t)n*64 + win)*4 + tid];
    __syncthreads();
    const float* kvbase = kvp + (size_t)n*(64*16*512);
    #pragma unroll
    for (int i = 0; i < 4; ++i) {
        int f = i*256 + tid;
        int e   = f >> 9;
        int key = (f >> 3) & 63;
        int d4  = f & 7;
        const float* src = kvbase + ((size_t)(sel[key>>4]*16 + (key&15)))*512
                         + (hd0+e)*32 + d4*4;
        *(float4*)&kb[e][key][d4*4] = *(const float4*)src;
        *(float4*)&vb[e][key][d4*4] = *(const float4*)(src + 256);
    }
    __syncthreads();

    int ph = tid >> 4, pw = tid & 15;
    int h = (win >> 3)*16 + ph, w = (win & 7)*16 + pw;
    size_t prow = (((size_t)n*128 + h)*128 + w)*256;

    #pragma unroll
    for (int e = 0; e < 2; ++e) {
        int coff = (hd0 + e)*32;
        float q[32];
        #pragma unroll
        for (int d4 = 0; d4 < 8; ++d4) {
            float4 f = *(const float4*)(qbuf + prow + coff + d4*4);
            q[d4*4+0]=f.x; q[d4*4+1]=f.y; q[d4*4+2]=f.z; q[d4*4+3]=f.w;
        }
        float o[32];
        #pragma unroll
        for (int d = 0; d < 32; ++d) o[d] = 0.f;
        float m = -3.0e38f, l = 0.f;
        #pragma unroll
        for (int c4 = 0; c4 < 4; ++c4) {
            float sc[16];
            float cmax = -3.0e38f;
            #pragma unroll
            for (int k = 0; k < 16; ++k) {
                const float* kr = &kb[e][c4*16 + k][0];
                float acc = 0.f;
                #pragma unroll
                for (int d4 = 0; d4 < 8; ++d4) {
                    float4 f = *(const float4*)(kr + d4*4);
                    acc += q[d4*4+0]*f.x + q[d4*4+1]*f.y
                         + q[d4*4+2]*f.z + q[d4*4+3]*f.w;
                }
                sc[k] = acc * SCALE_;
                cmax = fmaxf(cmax, sc[k]);
            }
            float newm = fmaxf(m, cmax);
            float alpha = __expf(m - newm);
            l *= alpha;
            #pragma unroll
            for (int d = 0; d < 32; ++d) o[d] *= alpha;
            #pragma unroll
            for (int k = 0; k < 16; ++k) {
                float p = __expf(sc[k] - newm);
                l += p;
                const float* vr = &vb[e][c4*16 + k][0];
                #pragma unroll
                for (int d4 = 0; d4 < 8; ++d4) {
                    float4 f = *(const float4*)(vr + d4*4);
                    o[d4*4+0] += p*f.x; o[d4*4+1] += p*f.y;
                    o[d4*4+2] += p*f.z; o[d4*4+3] += p*f.w;
                }
            }
            m = newm;
        }
        float inv = 1.f / l;
        float* op = out + prow + coff;
        #pragma unroll
        for (int d4 = 0; d4 < 8; ++d4) {
            float4 cur = *(const float4*)(op + d4*4);
            cur.x += o[d4*4+0]*inv; cur.y += o[d4*4+1]*inv;
            cur.z += o[d4*4+2]*inv; cur.w += o[d4*4+3]*inv;
            *(float4*)(op + d4*4) = cur;
        }
    }
}

extern "C" void kernel_launch(void* const* d_in, const int* in_sizes, int n_in,
                              void* d_out, int out_size, void* d_ws, size_t ws_size,
                              hipStream_t stream)
{
    const float* x1   = (const float*)d_in[0];
    const float* x2   = (const float*)d_in[1];
    const float* Wqkv = (const float*)d_in[2];
    const float* bqkv = (const float*)d_in[3];
    const float* lw   = (const float*)d_in[4];
    const float* lb   = (const float*)d_in[5];
    const float* Wo   = (const float*)d_in[6];
    const float* bo   = (const float*)d_in[7];
    float* out1 = (float*)d_out;
    float* out2 = out1 + (size_t)TOK_*C_;

    float* ws    = (float*)d_ws;
    float* xpool = ws;                          // 2,097,152 f
    float* xwm   = xpool + 2097152;             //   131,072 f
    float* kvp   = xwm   + 131072;              // 4,194,304 f
    float* qwin  = kvp   + 4194304;             //   131,072 f
    float* kwin  = qwin  + 131072;              //   131,072 f
    int*   idx   = (int*)(kwin + 131072);       //     2,048 i
    ushort* Wh   = (ushort*)(idx + 2048);       //   262,144 us (131,072 f)
    ushort* Wl   = Wh + 262144;                 //   262,144 us
    float* buf   = (float*)(Wl + 262144);       // 16,777,216 f

    // 0) pre-split weights (Wqkv rows 0-767, Wo rows 768-1023)
    wsplit_kernel<<<dim3(256), dim3(256), 0, stream>>>(Wqkv, Wo, Wh, Wl);
    // 1) pooled image + window means (both branches)
    pool_kernel<<<dim3(512), dim3(256), 0, stream>>>(x1, x2, xpool, xwm);
    // 2) kv_pool = xpool @ Wkv^T + bkv   (M=8192, NO=512)
    gemm_mfma<<<dim3(128,2), dim3(256), 0, stream>>>(xpool, Wh, Wl, 256, bqkv + 256, kvp, 512);
    // 3) window-mean projections (M=512)
    gemm_mfma<<<dim3(8,1), dim3(256), 0, stream>>>(xwm, Wh, Wl, 0,   bqkv,       qwin, 256);
    gemm_mfma<<<dim3(8,1), dim3(256), 0, stream>>>(xwm, Wh, Wl, 256, bqkv + 256, kwin, 256);
    // 4) routing (both pairs)
    route_kernel<<<dim3(512), dim3(64), 0, stream>>>(qwin, kwin, idx);
    // 5) v1 -> buf ; lepe1 = conv(v1) -> out1
    gemm_mfma<<<dim3(1024,1), dim3(256), 0, stream>>>(x1, Wh, Wl, 512, bqkv + 512, buf, 256);
    lepe_kernel<<<dim3(2048), dim3(256), 0, stream>>>(buf, lw, lb, out1);
    // 6) v2 -> buf ; lepe2 -> out2
    gemm_mfma<<<dim3(1024,1), dim3(256), 0, stream>>>(x2, Wh, Wl, 512, bqkv + 512, buf, 256);
    lepe_kernel<<<dim3(2048), dim3(256), 0, stream>>>(buf, lw, lb, out2);
    // 7) q2 -> buf ; attend(q2, kv1, idx1) += out1
    gemm_mfma<<<dim3(1024,1), dim3(256), 0, stream>>>(x2, Wh, Wl, 0, bqkv, buf, 256);
    attn_kernel<<<dim3(256,4), dim3(256), 0, stream>>>(buf, kvp, idx, out1);
    // 8) q1 -> buf ; attend(q1, kv2, idx2) += out2
    gemm_mfma<<<dim3(1024,1), dim3(256), 0, stream>>>(x1, Wh, Wl, 0, bqkv, buf, 256);
    attn_kernel<<<dim3(256,4), dim3(256), 0, stream>>>(buf, kvp + 2097152, idx + N_*64*4, out2);
    // 9) final projection, in-place on d_out (gridDim.y==1 -> safe)
    gemm_mfma<<<dim3(1024,1), dim3(256), 0, stream>>>(out1, Wh, Wl, 768, bo, out1, 256);
    gemm_mfma<<<dim3(1024,1), dim3(256), 0, stream>>>(out2, Wh, Wl, 768, bo, out2, 256);
}